// Round 8
// baseline (382.866 us; speedup 1.0000x reference)
//
#include <hip/hip_runtime.h>
#include <math.h>

#define NN 32768
#define NG 256
#define DEG 8
#define HC 256
#define NCAT 1088          // Q(256)|K(256)|V(256)|S(768..1023)|QE(1024..1087)
#define HCP 320            // H'(256) | zb(64)
#define KTOP 64
#define EPSBN 1e-5f

typedef __attribute__((ext_vector_type(8))) short short8v;   // 8 bf16
typedef __attribute__((ext_vector_type(4))) float f32x4;

// ---------------- bf16 helpers ----------------
__device__ inline float bf2f(unsigned short u) {
    union { unsigned int i; float f; } c; c.i = ((unsigned int)u) << 16; return c.f;
}
__device__ inline unsigned short f2bf(float f) {
    union { float f; unsigned int i; } c; c.f = f;
    unsigned int r = c.i + 0x7FFFu + ((c.i >> 16) & 1u);
    return (unsigned short)(r >> 16);
}
__device__ inline void split2(float v, unsigned short& hi, unsigned short& lo) {
    hi = f2bf(v);
    lo = f2bf(v - bf2f(hi));
}

// ---------------------------------------------------------------------------
// split_x: fp32 [NN,64] -> hi/lo bf16 pair (one-time, layer-1 A operand)
// ---------------------------------------------------------------------------
__global__ __launch_bounds__(256) void split_x(
    const float* __restrict__ X,
    unsigned short* __restrict__ Xhi, unsigned short* __restrict__ Xlo)
{
    size_t i8 = ((size_t)blockIdx.x * 256 + threadIdx.x) * 8;
    float4 a0 = *(const float4*)(X + i8);
    float4 a1 = *(const float4*)(X + i8 + 4);
    float av[8] = {a0.x, a0.y, a0.z, a0.w, a1.x, a1.y, a1.z, a1.w};
    short8v vh, vl;
    #pragma unroll
    for (int j = 0; j < 8; j++) {
        unsigned short h, l;
        split2(av[j], h, l);
        vh[j] = (short)h; vl[j] = (short)l;
    }
    *(short8v*)(Xhi + i8) = vh;
    *(short8v*)(Xlo + i8) = vl;
}

// ---------------------------------------------------------------------------
// prep: weights.
//  b 0..15 : WThi/WTlo [1088][64]
//  b 16    : bcat[1088], qe rows, Wbf[0..511] = [w13|w23], stats zero
//  b 17    : tWT cols 0..255 (stride 320)
//  b 18    : tWT cols 256..319 = (We_h @ tW_h)^T ; Wbf[512..575] = we13
// ---------------------------------------------------------------------------
__global__ __launch_bounds__(256) void prep(
    const float* __restrict__ Wq, const float* __restrict__ bq,
    const float* __restrict__ Wk, const float* __restrict__ bk,
    const float* __restrict__ Wv, const float* __restrict__ bv,
    const float* __restrict__ Ws, const float* __restrict__ bs,
    const float* __restrict__ We, const float* __restrict__ tW,
    const float* __restrict__ Wb,
    unsigned short* __restrict__ WThi, unsigned short* __restrict__ WTlo,
    float* __restrict__ bcat,
    unsigned short* __restrict__ tWThi, unsigned short* __restrict__ tWTlo,
    float* __restrict__ Wbf, float* __restrict__ stats)
{
    const int t = threadIdx.x, b = blockIdx.x;
    if (b < 16) {
        int n = b * 64 + (t >> 2);
        int cc = n & 255;
        const float* src = (n < 256) ? Wq : (n < 512) ? Wk : (n < 768) ? Wv : Ws;
        int k0 = (t & 3) * 16;
        for (int k = k0; k < k0 + 16; k++) {
            unsigned short h, l;
            split2(src[k * 256 + cc], h, l);
            WThi[n * 64 + k] = h; WTlo[n * 64 + k] = l;
        }
    } else if (b == 16) {
        if (t < 128) stats[t] = 0.f;
        Wbf[t]       = Wb[t]       + Wb[512 + t];   // w13
        Wbf[256 + t] = Wb[256 + t] - Wb[512 + t];   // w23
        for (int c = t; c < 1024; c += 256) {
            int cc = c & 255;
            bcat[c] = (c < 256) ? bq[cc] : (c < 512) ? bk[cc] : (c < 768) ? bv[cc] : bs[cc];
        }
        int o = t >> 2, h = o >> 4, f = o & 15;
        int k0 = (t & 3) * 16;
        for (int k = k0; k < k0 + 16; k++) {
            float s = 0.f;
            #pragma unroll
            for (int d = 0; d < 64; d++)
                s += Wq[k * 256 + h * 64 + d] * We[f * 256 + h * 64 + d];
            unsigned short hh, ll;
            split2(s, hh, ll);
            WThi[(1024 + o) * 64 + k] = hh; WTlo[(1024 + o) * 64 + k] = ll;
        }
        if ((t & 3) == 0) {
            float s = 0.f;
            #pragma unroll
            for (int d = 0; d < 64; d++)
                s += bq[h * 64 + d] * We[f * 256 + h * 64 + d];
            bcat[1024 + o] = s;
        }
    } else if (b == 17) {
        int n = t >> 2;
        int k0 = (t & 3) * 64;
        for (int k = k0; k < k0 + 64; k++) {
            unsigned short h, l;
            split2(tW[k * 64 + n], h, l);
            tWThi[n * HCP + k] = h; tWTlo[n * HCP + k] = l;
        }
    } else {
        // M[k'][n] = sum_d We[f][h*64+d] * tW[h*64+d][n],  k' = h*16+f
        int n = t >> 2;
        int k0 = (t & 3) * 16;
        for (int kp = k0; kp < k0 + 16; kp++) {
            int h = kp >> 4, f = kp & 15;
            float s = 0.f;
            #pragma unroll
            for (int d = 0; d < 64; d++)
                s += We[f * 256 + h * 64 + d] * tW[(h * 64 + d) * 64 + n];
            unsigned short hh, ll;
            split2(s, hh, ll);
            tWThi[n * HCP + 256 + kp] = hh; tWTlo[n * HCP + 256 + kp] = ll;
        }
        if (t < 64) {
            int h = t >> 4, f = t & 15;
            float s = 0.f;
            #pragma unroll
            for (int d = 0; d < 64; d++)
                s += We[f * 256 + h * 64 + d] * (Wb[h * 64 + d] + Wb[512 + h * 64 + d]);
            Wbf[512 + t] = s;                       // we13
        }
    }
}

// ---------------------------------------------------------------------------
// MFMA projection (split-bf16): C_bf16[M,1088] = A[M,64] @ W[64,1088] + bcat
// ---------------------------------------------------------------------------
__global__ __launch_bounds__(256) void proj_mfma(
    const unsigned short* __restrict__ Ahi, const unsigned short* __restrict__ Alo,
    const unsigned short* __restrict__ WThi, const unsigned short* __restrict__ WTlo,
    const float* __restrict__ bcat, unsigned short* __restrict__ C)
{
    __shared__ char smem[32768];
    unsigned short* AhiL = (unsigned short*)smem;            // [64][64]
    unsigned short* AloL = AhiL + 4096;
    unsigned short* WhiL = AloL + 4096;
    unsigned short* WloL = WhiL + 4096;
    float* CL = (float*)smem;                                // [64][68] reuse
    const int t = threadIdx.x;
    const int n0 = blockIdx.x * 64;
    const int row0 = blockIdx.y * 64;

    #pragma unroll
    for (int g = 0; g < 2; g++) {
        int idx = t * 8 + g * 2048;
        int r = idx >> 6, c = idx & 63;
        int ch = (c >> 3) ^ (r & 7);
        *(short8v*)(AhiL + r * 64 + ch * 8) =
            *(const short8v*)(Ahi + (size_t)(row0 + r) * 64 + c);
        *(short8v*)(AloL + r * 64 + ch * 8) =
            *(const short8v*)(Alo + (size_t)(row0 + r) * 64 + c);
        *(short8v*)(WhiL + r * 64 + ch * 8) =
            *(const short8v*)(WThi + (size_t)(n0 + r) * 64 + c);
        *(short8v*)(WloL + r * 64 + ch * 8) =
            *(const short8v*)(WTlo + (size_t)(n0 + r) * 64 + c);
    }
    __syncthreads();

    const int w = t >> 6, l = t & 63;
    const int lr = l & 15, lg = l >> 4, ls = l & 7;
    f32x4 acc[4] = {};
    #pragma unroll
    for (int kk = 0; kk < 2; kk++) {
        int ch = (kk * 4 + lg) ^ ls;
        short8v ah = *(short8v*)(AhiL + (w * 16 + lr) * 64 + ch * 8);
        short8v al = *(short8v*)(AloL + (w * 16 + lr) * 64 + ch * 8);
        #pragma unroll
        for (int nt = 0; nt < 4; nt++) {
            short8v bh = *(short8v*)(WhiL + (nt * 16 + lr) * 64 + ch * 8);
            short8v bl = *(short8v*)(WloL + (nt * 16 + lr) * 64 + ch * 8);
            acc[nt] = __builtin_amdgcn_mfma_f32_16x16x32_bf16(ah, bh, acc[nt], 0, 0, 0);
            acc[nt] = __builtin_amdgcn_mfma_f32_16x16x32_bf16(al, bh, acc[nt], 0, 0, 0);
            acc[nt] = __builtin_amdgcn_mfma_f32_16x16x32_bf16(ah, bl, acc[nt], 0, 0, 0);
        }
    }
    __syncthreads();
    #pragma unroll
    for (int nt = 0; nt < 4; nt++)
        #pragma unroll
        for (int r = 0; r < 4; r++)
            CL[(w * 16 + lg * 4 + r) * 68 + nt * 16 + lr] = acc[nt][r];
    __syncthreads();
    {
        int r = t >> 2, cb = (t & 3) * 16;
        #pragma unroll
        for (int jj = 0; jj < 2; jj++) {
            f32x4 p0 = *(f32x4*)(CL + r * 68 + cb + jj * 8);
            f32x4 p1 = *(f32x4*)(CL + r * 68 + cb + jj * 8 + 4);
            float4 b0 = *(const float4*)(bcat + n0 + cb + jj * 8);
            float4 b1 = *(const float4*)(bcat + n0 + cb + jj * 8 + 4);
            short8v o;
            o[0] = (short)f2bf(p0[0] + b0.x); o[1] = (short)f2bf(p0[1] + b0.y);
            o[2] = (short)f2bf(p0[2] + b0.z); o[3] = (short)f2bf(p0[3] + b0.w);
            o[4] = (short)f2bf(p1[0] + b1.x); o[5] = (short)f2bf(p1[1] + b1.y);
            o[6] = (short)f2bf(p1[2] + b1.z); o[7] = (short)f2bf(p1[3] + b1.w);
            *(short8v*)(C + (size_t)(row0 + r) * NCAT + n0 + cb + jj * 8) = o;
        }
    }
}

// ---------------------------------------------------------------------------
// MFMA transform (split-bf16): T_f32[M,64] = relu(A[M,320] @ W[320,64] + b)
// A = [H' | zb] (hi/lo pair). Epilogue accumulates BN stats via atomics.
// ---------------------------------------------------------------------------
__global__ __launch_bounds__(256) void gemm_t(
    const unsigned short* __restrict__ Ahi, const unsigned short* __restrict__ Alo,
    const unsigned short* __restrict__ WThi, const unsigned short* __restrict__ WTlo,
    const float* __restrict__ bias, float* __restrict__ Tout,
    float* __restrict__ stats)
{
    __shared__ char smem[32768];
    unsigned short* AhiL = (unsigned short*)smem;
    unsigned short* AloL = AhiL + 4096;
    unsigned short* WhiL = AloL + 4096;
    unsigned short* WloL = WhiL + 4096;
    float* CL = (float*)smem;
    const int t = threadIdx.x;
    const int row0 = blockIdx.x * 64;
    const int w = t >> 6, l = t & 63;
    const int lr = l & 15, lg = l >> 4, ls = l & 7;
    f32x4 acc[4] = {};
    for (int kt = 0; kt < 5; kt++) {
        if (kt) __syncthreads();
        #pragma unroll
        for (int g = 0; g < 2; g++) {
            int idx = t * 8 + g * 2048;
            int r = idx >> 6, c = idx & 63;
            int ch = (c >> 3) ^ (r & 7);
            *(short8v*)(AhiL + r * 64 + ch * 8) =
                *(const short8v*)(Ahi + (size_t)(row0 + r) * HCP + kt * 64 + c);
            *(short8v*)(AloL + r * 64 + ch * 8) =
                *(const short8v*)(Alo + (size_t)(row0 + r) * HCP + kt * 64 + c);
            *(short8v*)(WhiL + r * 64 + ch * 8) =
                *(const short8v*)(WThi + r * HCP + kt * 64 + c);
            *(short8v*)(WloL + r * 64 + ch * 8) =
                *(const short8v*)(WTlo + r * HCP + kt * 64 + c);
        }
        __syncthreads();
        #pragma unroll
        for (int kk = 0; kk < 2; kk++) {
            int ch = (kk * 4 + lg) ^ ls;
            short8v ah = *(short8v*)(AhiL + (w * 16 + lr) * 64 + ch * 8);
            short8v al = *(short8v*)(AloL + (w * 16 + lr) * 64 + ch * 8);
            #pragma unroll
            for (int nt = 0; nt < 4; nt++) {
                short8v bh = *(short8v*)(WhiL + (nt * 16 + lr) * 64 + ch * 8);
                short8v bl = *(short8v*)(WloL + (nt * 16 + lr) * 64 + ch * 8);
                acc[nt] = __builtin_amdgcn_mfma_f32_16x16x32_bf16(ah, bh, acc[nt], 0, 0, 0);
                acc[nt] = __builtin_amdgcn_mfma_f32_16x16x32_bf16(al, bh, acc[nt], 0, 0, 0);
                acc[nt] = __builtin_amdgcn_mfma_f32_16x16x32_bf16(ah, bl, acc[nt], 0, 0, 0);
            }
        }
    }
    __syncthreads();
    #pragma unroll
    for (int nt = 0; nt < 4; nt++)
        #pragma unroll
        for (int r = 0; r < 4; r++)
            CL[(w * 16 + lg * 4 + r) * 68 + nt * 16 + lr] = acc[nt][r];
    __syncthreads();
    {
        int r = t >> 2, cb = (t & 3) * 16;
        #pragma unroll
        for (int jj = 0; jj < 4; jj++) {
            f32x4 p = *(f32x4*)(CL + r * 68 + cb + jj * 4);
            float4 bb = *(const float4*)(bias + cb + jj * 4);
            float4 o;
            o.x = fmaxf(p[0] + bb.x, 0.f); o.y = fmaxf(p[1] + bb.y, 0.f);
            o.z = fmaxf(p[2] + bb.z, 0.f); o.w = fmaxf(p[3] + bb.w, 0.f);
            *(float4*)(Tout + (size_t)(row0 + r) * 64 + cb + jj * 4) = o;
        }
    }
    if (t < 64) {
        float bb = bias[t];
        float s = 0.f, s2 = 0.f;
        #pragma unroll 8
        for (int r = 0; r < 64; r++) {
            float v = fmaxf(CL[r * 68 + t] + bb, 0.f);
            s += v; s2 += v * v;
        }
        atomicAdd(&stats[t], s);
        atomicAdd(&stats[64 + t], s2);
    }
}

// ---------------------------------------------------------------------------
// Attention + beta gate (We term factored out). 2 nodes/wave, 32 lanes/node.
// Output: H'[NN,320] = [beta*xr+(1-beta)*attnV (256) | (1-beta)*z (64)]
// as bf16 hi/lo pair. Beta uses Wbf = [w13|w23|we13].
// ---------------------------------------------------------------------------
__global__ __launch_bounds__(256) void attn_fused(
    const unsigned short* __restrict__ C,
    const float* __restrict__ Wbf,
    const int* __restrict__ srcIdx, const float* __restrict__ EA,
    unsigned short* __restrict__ Hhi, unsigned short* __restrict__ Hlo)
{
    const int t = threadIdx.x;
    const int lane = t & 63;
    const int bid = blockIdx.x;
    const int swz = (bid & 7) * 512 + (bid >> 3);   // XCD-contiguous chunks
    const int n = swz * 8 + (t >> 5);               // 8 nodes per block
    const int l = lane & 31;                        // lane within node
    const int c0 = l * 8;                           // 8 channels
    const int h = l >> 3;                           // head
    const int fl = l & 7;                           // feature-pair / edge slot
    const int gb = lane & 56;                       // 8-lane head-group base

    const unsigned short* rowN = C + (size_t)n * NCAT;
    short8v qv = *(const short8v*)(rowN + c0);
    float q[8];
    #pragma unroll
    for (int i = 0; i < 8; i++) q[i] = bf2f((unsigned short)qv[i]);
    float qe0 = bf2f(rowN[1024 + h * 16 + 2 * fl]);
    float qe1 = bf2f(rowN[1024 + h * 16 + 2 * fl + 1]);

    const int ebase = n * DEG;
    int sj = srcIdx[ebase + fl];
    int ss[DEG];
    #pragma unroll
    for (int j = 0; j < DEG; j++) ss[j] = __shfl(sj, gb | j);

    // batched K + EA loads
    short8v kv[DEG];
    float2 eav[DEG];
    #pragma unroll
    for (int j = 0; j < DEG; j++) {
        kv[j] = *(const short8v*)(C + (size_t)ss[j] * NCAT + 256 + c0);
        eav[j] = *(const float2*)(EA + (size_t)(ebase + j) * 16 + 2 * fl);
    }
    float alpha[DEG];
    #pragma unroll
    for (int j = 0; j < DEG; j++) {
        float d = eav[j].x * qe0 + eav[j].y * qe1;
        #pragma unroll
        for (int i = 0; i < 8; i++) d += q[i] * bf2f((unsigned short)kv[j][i]);
        alpha[j] = d;
    }
    #pragma unroll
    for (int j = 0; j < DEG; j++) {
        float d = alpha[j];
        d += __shfl_xor(d, 1); d += __shfl_xor(d, 2); d += __shfl_xor(d, 4);
        alpha[j] = d * 0.125f;                      // 1/sqrt(64)
    }
    float mx = alpha[0];
    #pragma unroll
    for (int j = 1; j < DEG; j++) mx = fmaxf(mx, alpha[j]);
    float wsum = 0.f, wgt[DEG];
    #pragma unroll
    for (int j = 0; j < DEG; j++) { wgt[j] = expf(alpha[j] - mx); wsum += wgt[j]; }
    float inv = 1.f / wsum;

    // V gather + weighted sum; z accumulation
    float o[8] = {};
    float eg0 = 0.f, eg1 = 0.f;
    #pragma unroll
    for (int j = 0; j < DEG; j++) {
        float wj = wgt[j] * inv;
        eg0 += wj * eav[j].x; eg1 += wj * eav[j].y;
        short8v vv = *(const short8v*)(C + (size_t)ss[j] * NCAT + 512 + c0);
        #pragma unroll
        for (int i = 0; i < 8; i++) o[i] += wj * bf2f((unsigned short)vv[i]);
    }

    short8v sv = *(const short8v*)(rowN + 768 + c0);
    float xr[8];
    #pragma unroll
    for (int i = 0; i < 8; i++) xr[i] = bf2f((unsigned short)sv[i]);

    // beta logit: o'.w13 + xr.w23 + z.we13
    float2 we13 = *(const float2*)(Wbf + 512 + l * 2);
    float part = eg0 * we13.x + eg1 * we13.y;
    {
        f32x4 w13a = *(const f32x4*)(Wbf + c0);
        f32x4 w13b = *(const f32x4*)(Wbf + c0 + 4);
        f32x4 w23a = *(const f32x4*)(Wbf + 256 + c0);
        f32x4 w23b = *(const f32x4*)(Wbf + 256 + c0 + 4);
        #pragma unroll
        for (int i = 0; i < 4; i++) {
            part += o[i] * w13a[i] + xr[i] * w23a[i];
            part += o[4 + i] * w13b[i] + xr[4 + i] * w23b[i];
        }
    }
    part += __shfl_xor(part, 1);  part += __shfl_xor(part, 2);
    part += __shfl_xor(part, 4);  part += __shfl_xor(part, 8);
    part += __shfl_xor(part, 16);
    float beta = 1.f / (1.f + expf(-part));
    float omb = 1.f - beta;

    short8v hh, hl;
    #pragma unroll
    for (int i = 0; i < 8; i++) {
        float hv = beta * xr[i] + omb * o[i];
        unsigned short a, b;
        split2(hv, a, b);
        hh[i] = (short)a; hl[i] = (short)b;
    }
    *(short8v*)(Hhi + (size_t)n * HCP + c0) = hh;
    *(short8v*)(Hlo + (size_t)n * HCP + c0) = hl;

    // zb = (1-beta)*z  -> columns 256 + l*2, l*2+1
    ushort2 zh, zl;
    split2(omb * eg0, zh.x, zl.x);
    split2(omb * eg1, zh.y, zl.y);
    *(ushort2*)(Hhi + (size_t)n * HCP + 256 + l * 2) = zh;
    *(ushort2*)(Hlo + (size_t)n * HCP + 256 + l * 2) = zl;
}

// ---------------------------------------------------------------------------
// BN apply: normalize in place (f32) + emit bf16 hi/lo for next layer
// ---------------------------------------------------------------------------
__global__ __launch_bounds__(256) void bn_apply(
    float* __restrict__ T, const float* __restrict__ stats,
    const float* __restrict__ g, const float* __restrict__ b,
    unsigned short* __restrict__ Thi, unsigned short* __restrict__ Tlo)
{
    int i = blockIdx.x * 256 + threadIdx.x;
    int c = i & 63;
    float mean = stats[c] * (1.f / NN);
    float var  = stats[64 + c] * (1.f / NN) - mean * mean;
    float v = T[i];
    float r = g[c] * (v - mean) * rsqrtf(var + EPSBN) + b[c];
    T[i] = r;
    unsigned short h, l;
    split2(r, h, l);
    Thi[i] = h; Tlo[i] = l;
}

// ---------------------------------------------------------------------------
// TopK pooling + readout + MLP head. One block (128 threads) per graph.
// ---------------------------------------------------------------------------
__global__ __launch_bounds__(128) void pool_mlp(
    const float* __restrict__ Hn, const float* __restrict__ pw,
    const float* __restrict__ W1, const float* __restrict__ b1,
    const float* __restrict__ W2, const float* __restrict__ b2,
    const float* __restrict__ W3, const float* __restrict__ b3,
    float* __restrict__ out)
{
    __shared__ float sh[128][65];
    __shared__ float spw[64];
    __shared__ float sc[128];
    __shared__ float sscale[128];
    __shared__ int   skeep[128];
    __shared__ float rmax[2][64], rsum[2][64];
    __shared__ float srep[128];
    __shared__ float sh1[256];
    __shared__ float sh2[128];
    __shared__ float wred[2];
    const int g = blockIdx.x, t = threadIdx.x;

    for (int i = t; i < 128 * 64; i += 128) sh[i >> 6][i & 63] = Hn[(size_t)g * 128 * 64 + i];
    if (t < 64) spw[t] = pw[t];
    __syncthreads();

    float nw = 0.f;
    #pragma unroll
    for (int i = 0; i < 64; i++) { float w = spw[i]; nw += w * w; }
    float invn = rsqrtf(nw);

    float s = 0.f;
    #pragma unroll
    for (int i = 0; i < 64; i++) s += sh[t][i] * spw[i];
    s *= invn;
    sc[t] = s;
    __syncthreads();

    int rank = 0;
    for (int m = 0; m < 128; m++) {
        float sm = sc[m];
        rank += (sm > s) || (sm == s && m < t);
    }
    skeep[t] = (rank < KTOP);
    sscale[t] = tanhf(s);
    __syncthreads();

    {
        int c = t & 63, half = t >> 6;
        float mxv = -1e30f, sm = 0.f;
        for (int r = half * 64; r < half * 64 + 64; r++) {
            if (skeep[r]) {
                float v = sh[r][c] * sscale[r];
                mxv = fmaxf(mxv, v); sm += v;
            }
        }
        rmax[half][c] = mxv; rsum[half][c] = sm;
    }
    __syncthreads();
    if (t < 64) {
        srep[t] = fmaxf(rmax[0][t], rmax[1][t]);
        srep[64 + t] = (rsum[0][t] + rsum[1][t]) * (1.f / KTOP);
    }
    __syncthreads();

    #pragma unroll
    for (int jj = 0; jj < 2; jj++) {
        int j = t + jj * 128;
        float a = b1[j];
        for (int c2 = 0; c2 < 128; c2++) a += srep[c2] * W1[c2 * 256 + j];
        sh1[j] = fmaxf(a, 0.f);
    }
    __syncthreads();
    {
        float a = b2[t];
        for (int c2 = 0; c2 < 256; c2++) a += sh1[c2] * W2[c2 * 128 + t];
        sh2[t] = fmaxf(a, 0.f);
    }
    __syncthreads();
    float p = sh2[t] * W3[t];
    p += __shfl_xor(p, 1);  p += __shfl_xor(p, 2);  p += __shfl_xor(p, 4);
    p += __shfl_xor(p, 8);  p += __shfl_xor(p, 16); p += __shfl_xor(p, 32);
    if ((t & 63) == 0) wred[t >> 6] = p;
    __syncthreads();
    if (t == 0) out[g] = wred[0] + wred[1] + b3[0];
}

// ---------------------------------------------------------------------------
extern "C" void kernel_launch(void* const* d_in, const int* in_sizes, int n_in,
                              void* d_out, int out_size, void* d_ws, size_t ws_size,
                              hipStream_t stream)
{
    const float* x    = (const float*)d_in[0];
    const int*   ei   = (const int*)  d_in[1];
    const float* ea   = (const float*)d_in[2];
    const int*   srcI = ei;
    const float* Wq1 = (const float*)d_in[4];  const float* bq1 = (const float*)d_in[5];
    const float* Wk1 = (const float*)d_in[6];  const float* bk1 = (const float*)d_in[7];
    const float* Wv1 = (const float*)d_in[8];  const float* bv1 = (const float*)d_in[9];
    const float* We1 = (const float*)d_in[10];
    const float* Ws1 = (const float*)d_in[11]; const float* bs1 = (const float*)d_in[12];
    const float* Wb1 = (const float*)d_in[13];
    const float* t1W = (const float*)d_in[14]; const float* t1b = (const float*)d_in[15];
    const float* g1  = (const float*)d_in[16]; const float* be1 = (const float*)d_in[17];
    const float* Wq2 = (const float*)d_in[18]; const float* bq2 = (const float*)d_in[19];
    const float* Wk2 = (const float*)d_in[20]; const float* bk2 = (const float*)d_in[21];
    const float* Wv2 = (const float*)d_in[22]; const float* bv2 = (const float*)d_in[23];
    const float* We2 = (const float*)d_in[24];
    const float* Ws2 = (const float*)d_in[25]; const float* bs2 = (const float*)d_in[26];
    const float* Wb2 = (const float*)d_in[27];
    const float* t2W = (const float*)d_in[28]; const float* t2b = (const float*)d_in[29];
    const float* g2  = (const float*)d_in[30]; const float* be2 = (const float*)d_in[31];
    const float* pw  = (const float*)d_in[32];
    const float* l1W = (const float*)d_in[33]; const float* l1b = (const float*)d_in[34];
    const float* l2W = (const float*)d_in[35]; const float* l2b = (const float*)d_in[36];
    const float* l3W = (const float*)d_in[37]; const float* l3b = (const float*)d_in[38];

    char* ws = (char*)d_ws;
    unsigned short* C   = (unsigned short*)ws;                     // [NN,1088] bf16
    unsigned short* Hhi = (unsigned short*)(ws + (size_t)NN * NCAT * 2); // [NN,320]
    unsigned short* Hlo = Hhi + (size_t)NN * HCP;
    float* bT    = (float*)(Hlo + (size_t)NN * HCP);               // [NN,64] f32
    unsigned short* bThi = (unsigned short*)(bT + (size_t)NN * 64);
    unsigned short* bTlo = bThi + (size_t)NN * 64;
    unsigned short* Xhi  = bTlo + (size_t)NN * 64;
    unsigned short* Xlo  = Xhi + (size_t)NN * 64;
    float* bcat  = (float*)(Xlo + (size_t)NN * 64);                // [1088]
    float* stats = bcat + NCAT;                                    // [128]
    float* Wbf   = stats + 128;                                    // [576]
    unsigned short* WThi  = (unsigned short*)(Wbf + 576);          // [1088][64]
    unsigned short* WTlo  = WThi + (size_t)NCAT * 64;
    unsigned short* tWThi = WTlo + (size_t)NCAT * 64;              // [64][320]
    unsigned short* tWTlo = tWThi + 64 * HCP;

    const dim3 blk(256);
    const dim3 gProj(17, 512);

    // ---- layer 1 ----
    split_x<<<NN * 64 / (256 * 8), blk, 0, stream>>>(x, Xhi, Xlo);
    prep<<<19, blk, 0, stream>>>(Wq1, bq1, Wk1, bk1, Wv1, bv1, Ws1, bs1, We1, t1W, Wb1,
                                 WThi, WTlo, bcat, tWThi, tWTlo, Wbf, stats);
    proj_mfma<<<gProj, blk, 0, stream>>>(Xhi, Xlo, WThi, WTlo, bcat, C);
    attn_fused<<<NN / 8, blk, 0, stream>>>(C, Wbf, srcI, ea, Hhi, Hlo);
    gemm_t<<<512, blk, 0, stream>>>(Hhi, Hlo, tWThi, tWTlo, t1b, bT, stats);
    bn_apply<<<NN * 64 / 256, blk, 0, stream>>>(bT, stats, g1, be1, bThi, bTlo);

    // ---- layer 2 ----
    prep<<<19, blk, 0, stream>>>(Wq2, bq2, Wk2, bk2, Wv2, bv2, Ws2, bs2, We2, t2W, Wb2,
                                 WThi, WTlo, bcat, tWThi, tWTlo, Wbf, stats);
    proj_mfma<<<gProj, blk, 0, stream>>>(bThi, bTlo, WThi, WTlo, bcat, C);
    attn_fused<<<NN / 8, blk, 0, stream>>>(C, Wbf, srcI, ea, Hhi, Hlo);
    gemm_t<<<512, blk, 0, stream>>>(Hhi, Hlo, tWThi, tWTlo, t2b, bT, stats);
    bn_apply<<<NN * 64 / 256, blk, 0, stream>>>(bT, stats, g2, be2, bThi, bTlo);

    // ---- pooling + head ----
    pool_mlp<<<NG, 128, 0, stream>>>(bT, pw, l1W, l1b, l2W, l2b, l3W, l3b,
                                     (float*)d_out);
}

// Round 9
// 225.392 us; speedup vs baseline: 1.6987x; 1.6987x over previous
//
#include <hip/hip_runtime.h>
#include <math.h>

#define NN 32768
#define NG 256
#define DEG 8
#define HC 256
#define NCAT 1088          // Q(256)|K(256)|V(256)|S(768..1023)|QE(1024..1087)
#define HCP 320            // H'(256) | zb(64)
#define KTOP 64
#define EPSBN 1e-5f

typedef __attribute__((ext_vector_type(8))) short short8v;   // 8 bf16
typedef __attribute__((ext_vector_type(4))) float f32x4;

// ---------------- bf16 helpers ----------------
__device__ inline float bf2f(unsigned short u) {
    union { unsigned int i; float f; } c; c.i = ((unsigned int)u) << 16; return c.f;
}
__device__ inline unsigned short f2bf(float f) {
    union { float f; unsigned int i; } c; c.f = f;
    unsigned int r = c.i + 0x7FFFu + ((c.i >> 16) & 1u);
    return (unsigned short)(r >> 16);
}
__device__ inline void split2(float v, unsigned short& hi, unsigned short& lo) {
    hi = f2bf(v);
    lo = f2bf(v - bf2f(hi));
}

// ---------------------------------------------------------------------------
// split_x: fp32 [NN,64] -> hi/lo bf16 pair (one-time, layer-1 A operand)
// ---------------------------------------------------------------------------
__global__ __launch_bounds__(256) void split_x(
    const float* __restrict__ X,
    unsigned short* __restrict__ Xhi, unsigned short* __restrict__ Xlo)
{
    size_t i8 = ((size_t)blockIdx.x * 256 + threadIdx.x) * 8;
    float4 a0 = *(const float4*)(X + i8);
    float4 a1 = *(const float4*)(X + i8 + 4);
    float av[8] = {a0.x, a0.y, a0.z, a0.w, a1.x, a1.y, a1.z, a1.w};
    short8v vh, vl;
    #pragma unroll
    for (int j = 0; j < 8; j++) {
        unsigned short h, l;
        split2(av[j], h, l);
        vh[j] = (short)h; vl[j] = (short)l;
    }
    *(short8v*)(Xhi + i8) = vh;
    *(short8v*)(Xlo + i8) = vl;
}

// ---------------------------------------------------------------------------
// prep (parallelized, 65 blocks):
//  b 0..15 : WThi/WTlo rows 0..1023 (transposed QKVS weights)
//  b 16..31: qe rows 1024..1087 — one thread per (k,o) dot
//  b 32..47: M = (We_h @ tW_h)^T -> tWT cols 256..319 — one thread per (kp,n)
//  b 48..63: tWT cols 0..255 (transposed tW), 4 elems/thread
//  b 64    : bcat, Wbf=[w13|w23|we13], qe bias, stats zero
// ---------------------------------------------------------------------------
__global__ __launch_bounds__(256) void prep(
    const float* __restrict__ Wq, const float* __restrict__ bq,
    const float* __restrict__ Wk, const float* __restrict__ bk,
    const float* __restrict__ Wv, const float* __restrict__ bv,
    const float* __restrict__ Ws, const float* __restrict__ bs,
    const float* __restrict__ We, const float* __restrict__ tW,
    const float* __restrict__ Wb,
    unsigned short* __restrict__ WThi, unsigned short* __restrict__ WTlo,
    float* __restrict__ bcat,
    unsigned short* __restrict__ tWThi, unsigned short* __restrict__ tWTlo,
    float* __restrict__ Wbf, float* __restrict__ stats)
{
    const int t = threadIdx.x, b = blockIdx.x;
    if (b < 16) {
        int n = b * 64 + (t >> 2);
        int cc = n & 255;
        const float* src = (n < 256) ? Wq : (n < 512) ? Wk : (n < 768) ? Wv : Ws;
        int k0 = (t & 3) * 16;
        #pragma unroll
        for (int k = k0; k < k0 + 16; k++) {
            unsigned short h, l;
            split2(src[k * 256 + cc], h, l);
            WThi[n * 64 + k] = h; WTlo[n * 64 + k] = l;
        }
    } else if (b < 32) {
        // qe[k][o] = sum_d Wq[k][h*64+d] * We[f][h*64+d]
        int idx = (b - 16) * 256 + t;
        int k = idx >> 6, o = idx & 63;
        int h = o >> 4, f = o & 15;
        const float* wq = Wq + k * 256 + h * 64;
        const float* we = We + f * 256 + h * 64;
        float s = 0.f;
        #pragma unroll
        for (int d = 0; d < 64; d++) s += wq[d] * we[d];
        unsigned short hh, ll;
        split2(s, hh, ll);
        WThi[(1024 + o) * 64 + k] = hh; WTlo[(1024 + o) * 64 + k] = ll;
    } else if (b < 48) {
        // M[kp][n] = sum_d We[f][h*64+d] * tW[h*64+d][n]
        int idx = (b - 32) * 256 + t;
        int kp = idx >> 6, n = idx & 63;
        int h = kp >> 4, f = kp & 15;
        const float* we = We + f * 256 + h * 64;
        const float* tw = tW + (h * 64) * 64 + n;
        float s = 0.f;
        #pragma unroll
        for (int d = 0; d < 64; d++) s += we[d] * tw[d * 64];
        unsigned short hh, ll;
        split2(s, hh, ll);
        tWThi[n * HCP + 256 + kp] = hh; tWTlo[n * HCP + 256 + kp] = ll;
    } else if (b < 64) {
        int base = (b - 48) * 1024 + t * 4;
        #pragma unroll
        for (int i = 0; i < 4; i++) {
            int idx = base + i;
            int n = idx >> 8, k = idx & 255;
            unsigned short h, l;
            split2(tW[k * 64 + n], h, l);
            tWThi[n * HCP + k] = h; tWTlo[n * HCP + k] = l;
        }
    } else {
        if (t < 128) stats[t] = 0.f;
        Wbf[t]       = Wb[t]       + Wb[512 + t];   // w13
        Wbf[256 + t] = Wb[256 + t] - Wb[512 + t];   // w23
        for (int c = t; c < 1024; c += 256) {
            int cc = c & 255;
            bcat[c] = (c < 256) ? bq[cc] : (c < 512) ? bk[cc] : (c < 768) ? bv[cc] : bs[cc];
        }
        if (t < 64) {
            int h = t >> 4, f = t & 15;
            const float* we = We + f * 256 + h * 64;
            float s = 0.f, sb = 0.f;
            #pragma unroll
            for (int d = 0; d < 64; d++) {
                s  += we[d] * (Wb[h * 64 + d] + Wb[512 + h * 64 + d]);
                sb += we[d] * bq[h * 64 + d];
            }
            Wbf[512 + t] = s;        // we13
            bcat[1024 + t] = sb;     // qe bias
        }
    }
}

// ---------------------------------------------------------------------------
// MFMA projection (split-bf16): C_bf16[M,1088] = A[M,64] @ W[64,1088] + bcat
// ---------------------------------------------------------------------------
__global__ __launch_bounds__(256) void proj_mfma(
    const unsigned short* __restrict__ Ahi, const unsigned short* __restrict__ Alo,
    const unsigned short* __restrict__ WThi, const unsigned short* __restrict__ WTlo,
    const float* __restrict__ bcat, unsigned short* __restrict__ C)
{
    __shared__ char smem[32768];
    unsigned short* AhiL = (unsigned short*)smem;            // [64][64]
    unsigned short* AloL = AhiL + 4096;
    unsigned short* WhiL = AloL + 4096;
    unsigned short* WloL = WhiL + 4096;
    float* CL = (float*)smem;                                // [64][68] reuse
    const int t = threadIdx.x;
    const int n0 = blockIdx.x * 64;
    const int row0 = blockIdx.y * 64;

    #pragma unroll
    for (int g = 0; g < 2; g++) {
        int idx = t * 8 + g * 2048;
        int r = idx >> 6, c = idx & 63;
        int ch = (c >> 3) ^ (r & 7);
        *(short8v*)(AhiL + r * 64 + ch * 8) =
            *(const short8v*)(Ahi + (size_t)(row0 + r) * 64 + c);
        *(short8v*)(AloL + r * 64 + ch * 8) =
            *(const short8v*)(Alo + (size_t)(row0 + r) * 64 + c);
        *(short8v*)(WhiL + r * 64 + ch * 8) =
            *(const short8v*)(WThi + (size_t)(n0 + r) * 64 + c);
        *(short8v*)(WloL + r * 64 + ch * 8) =
            *(const short8v*)(WTlo + (size_t)(n0 + r) * 64 + c);
    }
    __syncthreads();

    const int w = t >> 6, l = t & 63;
    const int lr = l & 15, lg = l >> 4, ls = l & 7;
    f32x4 acc[4] = {};
    #pragma unroll
    for (int kk = 0; kk < 2; kk++) {
        int ch = (kk * 4 + lg) ^ ls;
        short8v ah = *(short8v*)(AhiL + (w * 16 + lr) * 64 + ch * 8);
        short8v al = *(short8v*)(AloL + (w * 16 + lr) * 64 + ch * 8);
        #pragma unroll
        for (int nt = 0; nt < 4; nt++) {
            short8v bh = *(short8v*)(WhiL + (nt * 16 + lr) * 64 + ch * 8);
            short8v bl = *(short8v*)(WloL + (nt * 16 + lr) * 64 + ch * 8);
            acc[nt] = __builtin_amdgcn_mfma_f32_16x16x32_bf16(ah, bh, acc[nt], 0, 0, 0);
            acc[nt] = __builtin_amdgcn_mfma_f32_16x16x32_bf16(al, bh, acc[nt], 0, 0, 0);
            acc[nt] = __builtin_amdgcn_mfma_f32_16x16x32_bf16(ah, bl, acc[nt], 0, 0, 0);
        }
    }
    __syncthreads();
    #pragma unroll
    for (int nt = 0; nt < 4; nt++)
        #pragma unroll
        for (int r = 0; r < 4; r++)
            CL[(w * 16 + lg * 4 + r) * 68 + nt * 16 + lr] = acc[nt][r];
    __syncthreads();
    {
        int r = t >> 2, cb = (t & 3) * 16;
        #pragma unroll
        for (int jj = 0; jj < 2; jj++) {
            f32x4 p0 = *(f32x4*)(CL + r * 68 + cb + jj * 8);
            f32x4 p1 = *(f32x4*)(CL + r * 68 + cb + jj * 8 + 4);
            float4 b0 = *(const float4*)(bcat + n0 + cb + jj * 8);
            float4 b1 = *(const float4*)(bcat + n0 + cb + jj * 8 + 4);
            short8v o;
            o[0] = (short)f2bf(p0[0] + b0.x); o[1] = (short)f2bf(p0[1] + b0.y);
            o[2] = (short)f2bf(p0[2] + b0.z); o[3] = (short)f2bf(p0[3] + b0.w);
            o[4] = (short)f2bf(p1[0] + b1.x); o[5] = (short)f2bf(p1[1] + b1.y);
            o[6] = (short)f2bf(p1[2] + b1.z); o[7] = (short)f2bf(p1[3] + b1.w);
            *(short8v*)(C + (size_t)(row0 + r) * NCAT + n0 + cb + jj * 8) = o;
        }
    }
}

// ---------------------------------------------------------------------------
// MFMA transform (split-bf16): T_f32[M,64] = relu(A[M,320] @ W[320,64] + b)
// A = [H' | zb] (hi/lo pair). Epilogue accumulates BN stats via atomics.
// ---------------------------------------------------------------------------
__global__ __launch_bounds__(256) void gemm_t(
    const unsigned short* __restrict__ Ahi, const unsigned short* __restrict__ Alo,
    const unsigned short* __restrict__ WThi, const unsigned short* __restrict__ WTlo,
    const float* __restrict__ bias, float* __restrict__ Tout,
    float* __restrict__ stats)
{
    __shared__ char smem[32768];
    unsigned short* AhiL = (unsigned short*)smem;
    unsigned short* AloL = AhiL + 4096;
    unsigned short* WhiL = AloL + 4096;
    unsigned short* WloL = WhiL + 4096;
    float* CL = (float*)smem;
    const int t = threadIdx.x;
    const int row0 = blockIdx.x * 64;
    const int w = t >> 6, l = t & 63;
    const int lr = l & 15, lg = l >> 4, ls = l & 7;
    f32x4 acc[4] = {};
    for (int kt = 0; kt < 5; kt++) {
        if (kt) __syncthreads();
        #pragma unroll
        for (int g = 0; g < 2; g++) {
            int idx = t * 8 + g * 2048;
            int r = idx >> 6, c = idx & 63;
            int ch = (c >> 3) ^ (r & 7);
            *(short8v*)(AhiL + r * 64 + ch * 8) =
                *(const short8v*)(Ahi + (size_t)(row0 + r) * HCP + kt * 64 + c);
            *(short8v*)(AloL + r * 64 + ch * 8) =
                *(const short8v*)(Alo + (size_t)(row0 + r) * HCP + kt * 64 + c);
            *(short8v*)(WhiL + r * 64 + ch * 8) =
                *(const short8v*)(WThi + r * HCP + kt * 64 + c);
            *(short8v*)(WloL + r * 64 + ch * 8) =
                *(const short8v*)(WTlo + r * HCP + kt * 64 + c);
        }
        __syncthreads();
        #pragma unroll
        for (int kk = 0; kk < 2; kk++) {
            int ch = (kk * 4 + lg) ^ ls;
            short8v ah = *(short8v*)(AhiL + (w * 16 + lr) * 64 + ch * 8);
            short8v al = *(short8v*)(AloL + (w * 16 + lr) * 64 + ch * 8);
            #pragma unroll
            for (int nt = 0; nt < 4; nt++) {
                short8v bh = *(short8v*)(WhiL + (nt * 16 + lr) * 64 + ch * 8);
                short8v bl = *(short8v*)(WloL + (nt * 16 + lr) * 64 + ch * 8);
                acc[nt] = __builtin_amdgcn_mfma_f32_16x16x32_bf16(ah, bh, acc[nt], 0, 0, 0);
                acc[nt] = __builtin_amdgcn_mfma_f32_16x16x32_bf16(al, bh, acc[nt], 0, 0, 0);
                acc[nt] = __builtin_amdgcn_mfma_f32_16x16x32_bf16(ah, bl, acc[nt], 0, 0, 0);
            }
        }
    }
    __syncthreads();
    #pragma unroll
    for (int nt = 0; nt < 4; nt++)
        #pragma unroll
        for (int r = 0; r < 4; r++)
            CL[(w * 16 + lg * 4 + r) * 68 + nt * 16 + lr] = acc[nt][r];
    __syncthreads();
    {
        int r = t >> 2, cb = (t & 3) * 16;
        #pragma unroll
        for (int jj = 0; jj < 4; jj++) {
            f32x4 p = *(f32x4*)(CL + r * 68 + cb + jj * 4);
            float4 bb = *(const float4*)(bias + cb + jj * 4);
            float4 o;
            o.x = fmaxf(p[0] + bb.x, 0.f); o.y = fmaxf(p[1] + bb.y, 0.f);
            o.z = fmaxf(p[2] + bb.z, 0.f); o.w = fmaxf(p[3] + bb.w, 0.f);
            *(float4*)(Tout + (size_t)(row0 + r) * 64 + cb + jj * 4) = o;
        }
    }
    if (t < 64) {
        float bb = bias[t];
        float s = 0.f, s2 = 0.f;
        #pragma unroll 8
        for (int r = 0; r < 64; r++) {
            float v = fmaxf(CL[r * 68 + t] + bb, 0.f);
            s += v; s2 += v * v;
        }
        atomicAdd(&stats[t], s);
        atomicAdd(&stats[64 + t], s2);
    }
}

// ---------------------------------------------------------------------------
// Attention + beta gate (We term factored out). 2 nodes/wave, 32 lanes/node.
// Output: H'[NN,320] = [beta*xr+(1-beta)*attnV (256) | (1-beta)*z (64)]
// ---------------------------------------------------------------------------
__global__ __launch_bounds__(256) void attn_fused(
    const unsigned short* __restrict__ C,
    const float* __restrict__ Wbf,
    const int* __restrict__ srcIdx, const float* __restrict__ EA,
    unsigned short* __restrict__ Hhi, unsigned short* __restrict__ Hlo)
{
    const int t = threadIdx.x;
    const int lane = t & 63;
    const int bid = blockIdx.x;
    const int swz = (bid & 7) * 512 + (bid >> 3);   // XCD-contiguous chunks
    const int n = swz * 8 + (t >> 5);               // 8 nodes per block
    const int l = lane & 31;                        // lane within node
    const int c0 = l * 8;                           // 8 channels
    const int h = l >> 3;                           // head
    const int fl = l & 7;                           // feature-pair / edge slot
    const int gb = lane & 56;                       // 8-lane head-group base

    const unsigned short* rowN = C + (size_t)n * NCAT;
    short8v qv = *(const short8v*)(rowN + c0);
    float q[8];
    #pragma unroll
    for (int i = 0; i < 8; i++) q[i] = bf2f((unsigned short)qv[i]);
    float qe0 = bf2f(rowN[1024 + h * 16 + 2 * fl]);
    float qe1 = bf2f(rowN[1024 + h * 16 + 2 * fl + 1]);

    const int ebase = n * DEG;
    int sj = srcIdx[ebase + fl];
    int ss[DEG];
    #pragma unroll
    for (int j = 0; j < DEG; j++) ss[j] = __shfl(sj, gb | j);

    // batched K + EA loads
    short8v kv[DEG];
    float2 eav[DEG];
    #pragma unroll
    for (int j = 0; j < DEG; j++) {
        kv[j] = *(const short8v*)(C + (size_t)ss[j] * NCAT + 256 + c0);
        eav[j] = *(const float2*)(EA + (size_t)(ebase + j) * 16 + 2 * fl);
    }
    float alpha[DEG];
    #pragma unroll
    for (int j = 0; j < DEG; j++) {
        float d = eav[j].x * qe0 + eav[j].y * qe1;
        #pragma unroll
        for (int i = 0; i < 8; i++) d += q[i] * bf2f((unsigned short)kv[j][i]);
        alpha[j] = d;
    }
    #pragma unroll
    for (int j = 0; j < DEG; j++) {
        float d = alpha[j];
        d += __shfl_xor(d, 1); d += __shfl_xor(d, 2); d += __shfl_xor(d, 4);
        alpha[j] = d * 0.125f;                      // 1/sqrt(64)
    }
    float mx = alpha[0];
    #pragma unroll
    for (int j = 1; j < DEG; j++) mx = fmaxf(mx, alpha[j]);
    float wsum = 0.f, wgt[DEG];
    #pragma unroll
    for (int j = 0; j < DEG; j++) { wgt[j] = expf(alpha[j] - mx); wsum += wgt[j]; }
    float inv = 1.f / wsum;

    // V gather + weighted sum; z accumulation
    float o[8] = {};
    float eg0 = 0.f, eg1 = 0.f;
    #pragma unroll
    for (int j = 0; j < DEG; j++) {
        float wj = wgt[j] * inv;
        eg0 += wj * eav[j].x; eg1 += wj * eav[j].y;
        short8v vv = *(const short8v*)(C + (size_t)ss[j] * NCAT + 512 + c0);
        #pragma unroll
        for (int i = 0; i < 8; i++) o[i] += wj * bf2f((unsigned short)vv[i]);
    }

    short8v sv = *(const short8v*)(rowN + 768 + c0);
    float xr[8];
    #pragma unroll
    for (int i = 0; i < 8; i++) xr[i] = bf2f((unsigned short)sv[i]);

    // beta logit: o'.w13 + xr.w23 + z.we13
    float2 we13 = *(const float2*)(Wbf + 512 + l * 2);
    float part = eg0 * we13.x + eg1 * we13.y;
    {
        f32x4 w13a = *(const f32x4*)(Wbf + c0);
        f32x4 w13b = *(const f32x4*)(Wbf + c0 + 4);
        f32x4 w23a = *(const f32x4*)(Wbf + 256 + c0);
        f32x4 w23b = *(const f32x4*)(Wbf + 256 + c0 + 4);
        #pragma unroll
        for (int i = 0; i < 4; i++) {
            part += o[i] * w13a[i] + xr[i] * w23a[i];
            part += o[4 + i] * w13b[i] + xr[4 + i] * w23b[i];
        }
    }
    part += __shfl_xor(part, 1);  part += __shfl_xor(part, 2);
    part += __shfl_xor(part, 4);  part += __shfl_xor(part, 8);
    part += __shfl_xor(part, 16);
    float beta = 1.f / (1.f + expf(-part));
    float omb = 1.f - beta;

    short8v hh, hl;
    #pragma unroll
    for (int i = 0; i < 8; i++) {
        float hv = beta * xr[i] + omb * o[i];
        unsigned short a, b;
        split2(hv, a, b);
        hh[i] = (short)a; hl[i] = (short)b;
    }
    *(short8v*)(Hhi + (size_t)n * HCP + c0) = hh;
    *(short8v*)(Hlo + (size_t)n * HCP + c0) = hl;

    // zb = (1-beta)*z  -> columns 256 + l*2, l*2+1
    ushort2 zh, zl;
    split2(omb * eg0, zh.x, zl.x);
    split2(omb * eg1, zh.y, zl.y);
    *(ushort2*)(Hhi + (size_t)n * HCP + 256 + l * 2) = zh;
    *(ushort2*)(Hlo + (size_t)n * HCP + 256 + l * 2) = zl;
}

// ---------------------------------------------------------------------------
// BN apply: normalize in place (f32) + emit bf16 hi/lo for next layer
// ---------------------------------------------------------------------------
__global__ __launch_bounds__(256) void bn_apply(
    float* __restrict__ T, const float* __restrict__ stats,
    const float* __restrict__ g, const float* __restrict__ b,
    unsigned short* __restrict__ Thi, unsigned short* __restrict__ Tlo)
{
    int i = blockIdx.x * 256 + threadIdx.x;
    int c = i & 63;
    float mean = stats[c] * (1.f / NN);
    float var  = stats[64 + c] * (1.f / NN) - mean * mean;
    float v = T[i];
    float r = g[c] * (v - mean) * rsqrtf(var + EPSBN) + b[c];
    T[i] = r;
    unsigned short h, l;
    split2(r, h, l);
    Thi[i] = h; Tlo[i] = l;
}

// ---------------------------------------------------------------------------
// TopK pooling + readout + MLP head. One block (128 threads) per graph.
// ---------------------------------------------------------------------------
__global__ __launch_bounds__(128) void pool_mlp(
    const float* __restrict__ Hn, const float* __restrict__ pw,
    const float* __restrict__ W1, const float* __restrict__ b1,
    const float* __restrict__ W2, const float* __restrict__ b2,
    const float* __restrict__ W3, const float* __restrict__ b3,
    float* __restrict__ out)
{
    __shared__ float sh[128][65];
    __shared__ float spw[64];
    __shared__ float sc[128];
    __shared__ float sscale[128];
    __shared__ int   skeep[128];
    __shared__ float rmax[2][64], rsum[2][64];
    __shared__ float srep[128];
    __shared__ float sh1[256];
    __shared__ float sh2[128];
    __shared__ float wred[2];
    const int g = blockIdx.x, t = threadIdx.x;

    for (int i = t; i < 128 * 64; i += 128) sh[i >> 6][i & 63] = Hn[(size_t)g * 128 * 64 + i];
    if (t < 64) spw[t] = pw[t];
    __syncthreads();

    float nw = 0.f;
    #pragma unroll
    for (int i = 0; i < 64; i++) { float w = spw[i]; nw += w * w; }
    float invn = rsqrtf(nw);

    float s = 0.f;
    #pragma unroll
    for (int i = 0; i < 64; i++) s += sh[t][i] * spw[i];
    s *= invn;
    sc[t] = s;
    __syncthreads();

    int rank = 0;
    for (int m = 0; m < 128; m++) {
        float sm = sc[m];
        rank += (sm > s) || (sm == s && m < t);
    }
    skeep[t] = (rank < KTOP);
    sscale[t] = tanhf(s);
    __syncthreads();

    {
        int c = t & 63, half = t >> 6;
        float mxv = -1e30f, sm = 0.f;
        for (int r = half * 64; r < half * 64 + 64; r++) {
            if (skeep[r]) {
                float v = sh[r][c] * sscale[r];
                mxv = fmaxf(mxv, v); sm += v;
            }
        }
        rmax[half][c] = mxv; rsum[half][c] = sm;
    }
    __syncthreads();
    if (t < 64) {
        srep[t] = fmaxf(rmax[0][t], rmax[1][t]);
        srep[64 + t] = (rsum[0][t] + rsum[1][t]) * (1.f / KTOP);
    }
    __syncthreads();

    #pragma unroll
    for (int jj = 0; jj < 2; jj++) {
        int j = t + jj * 128;
        float a = b1[j];
        for (int c2 = 0; c2 < 128; c2++) a += srep[c2] * W1[c2 * 256 + j];
        sh1[j] = fmaxf(a, 0.f);
    }
    __syncthreads();
    {
        float a = b2[t];
        for (int c2 = 0; c2 < 256; c2++) a += sh1[c2] * W2[c2 * 128 + t];
        sh2[t] = fmaxf(a, 0.f);
    }
    __syncthreads();
    float p = sh2[t] * W3[t];
    p += __shfl_xor(p, 1);  p += __shfl_xor(p, 2);  p += __shfl_xor(p, 4);
    p += __shfl_xor(p, 8);  p += __shfl_xor(p, 16); p += __shfl_xor(p, 32);
    if ((t & 63) == 0) wred[t >> 6] = p;
    __syncthreads();
    if (t == 0) out[g] = wred[0] + wred[1] + b3[0];
}

// ---------------------------------------------------------------------------
extern "C" void kernel_launch(void* const* d_in, const int* in_sizes, int n_in,
                              void* d_out, int out_size, void* d_ws, size_t ws_size,
                              hipStream_t stream)
{
    const float* x    = (const float*)d_in[0];
    const int*   ei   = (const int*)  d_in[1];
    const float* ea   = (const float*)d_in[2];
    const int*   srcI = ei;
    const float* Wq1 = (const float*)d_in[4];  const float* bq1 = (const float*)d_in[5];
    const float* Wk1 = (const float*)d_in[6];  const float* bk1 = (const float*)d_in[7];
    const float* Wv1 = (const float*)d_in[8];  const float* bv1 = (const float*)d_in[9];
    const float* We1 = (const float*)d_in[10];
    const float* Ws1 = (const float*)d_in[11]; const float* bs1 = (const float*)d_in[12];
    const float* Wb1 = (const float*)d_in[13];
    const float* t1W = (const float*)d_in[14]; const float* t1b = (const float*)d_in[15];
    const float* g1  = (const float*)d_in[16]; const float* be1 = (const float*)d_in[17];
    const float* Wq2 = (const float*)d_in[18]; const float* bq2 = (const float*)d_in[19];
    const float* Wk2 = (const float*)d_in[20]; const float* bk2 = (const float*)d_in[21];
    const float* Wv2 = (const float*)d_in[22]; const float* bv2 = (const float*)d_in[23];
    const float* We2 = (const float*)d_in[24];
    const float* Ws2 = (const float*)d_in[25]; const float* bs2 = (const float*)d_in[26];
    const float* Wb2 = (const float*)d_in[27];
    const float* t2W = (const float*)d_in[28]; const float* t2b = (const float*)d_in[29];
    const float* g2  = (const float*)d_in[30]; const float* be2 = (const float*)d_in[31];
    const float* pw  = (const float*)d_in[32];
    const float* l1W = (const float*)d_in[33]; const float* l1b = (const float*)d_in[34];
    const float* l2W = (const float*)d_in[35]; const float* l2b = (const float*)d_in[36];
    const float* l3W = (const float*)d_in[37]; const float* l3b = (const float*)d_in[38];

    char* ws = (char*)d_ws;
    unsigned short* C   = (unsigned short*)ws;                     // [NN,1088] bf16
    unsigned short* Hhi = (unsigned short*)(ws + (size_t)NN * NCAT * 2); // [NN,320]
    unsigned short* Hlo = Hhi + (size_t)NN * HCP;
    float* bT    = (float*)(Hlo + (size_t)NN * HCP);               // [NN,64] f32
    unsigned short* bThi = (unsigned short*)(bT + (size_t)NN * 64);
    unsigned short* bTlo = bThi + (size_t)NN * 64;
    unsigned short* Xhi  = bTlo + (size_t)NN * 64;
    unsigned short* Xlo  = Xhi + (size_t)NN * 64;
    float* bcat  = (float*)(Xlo + (size_t)NN * 64);                // [1088]
    float* stats = bcat + NCAT;                                    // [128]
    float* Wbf   = stats + 128;                                    // [576]
    unsigned short* WThi  = (unsigned short*)(Wbf + 576);          // [1088][64]
    unsigned short* WTlo  = WThi + (size_t)NCAT * 64;
    unsigned short* tWThi = WTlo + (size_t)NCAT * 64;              // [64][320]
    unsigned short* tWTlo = tWThi + 64 * HCP;

    const dim3 blk(256);
    const dim3 gProj(17, 512);

    // ---- layer 1 ----
    split_x<<<NN * 64 / (256 * 8), blk, 0, stream>>>(x, Xhi, Xlo);
    prep<<<65, blk, 0, stream>>>(Wq1, bq1, Wk1, bk1, Wv1, bv1, Ws1, bs1, We1, t1W, Wb1,
                                 WThi, WTlo, bcat, tWThi, tWTlo, Wbf, stats);
    proj_mfma<<<gProj, blk, 0, stream>>>(Xhi, Xlo, WThi, WTlo, bcat, C);
    attn_fused<<<NN / 8, blk, 0, stream>>>(C, Wbf, srcI, ea, Hhi, Hlo);
    gemm_t<<<512, blk, 0, stream>>>(Hhi, Hlo, tWThi, tWTlo, t1b, bT, stats);
    bn_apply<<<NN * 64 / 256, blk, 0, stream>>>(bT, stats, g1, be1, bThi, bTlo);

    // ---- layer 2 ----
    prep<<<65, blk, 0, stream>>>(Wq2, bq2, Wk2, bk2, Wv2, bv2, Ws2, bs2, We2, t2W, Wb2,
                                 WThi, WTlo, bcat, tWThi, tWTlo, Wbf, stats);
    proj_mfma<<<gProj, blk, 0, stream>>>(bThi, bTlo, WThi, WTlo, bcat, C);
    attn_fused<<<NN / 8, blk, 0, stream>>>(C, Wbf, srcI, ea, Hhi, Hlo);
    gemm_t<<<512, blk, 0, stream>>>(Hhi, Hlo, tWThi, tWTlo, t2b, bT, stats);
    bn_apply<<<NN * 64 / 256, blk, 0, stream>>>(bT, stats, g2, be2, bThi, bTlo);

    // ---- pooling + head ----
    pool_mlp<<<NG, 128, 0, stream>>>(bT, pw, l1W, l1b, l2W, l2b, l3W, l3b,
                                     (float*)d_out);
}

// Round 10
// 220.124 us; speedup vs baseline: 1.7393x; 1.0239x over previous
//
#include <hip/hip_runtime.h>
#include <math.h>

#define NN 32768
#define NG 256
#define DEG 8
#define HC 256
#define NCAT 1088          // Q(256)|K(256)|V(256)|S(768..1023)|QE(1024..1087)
#define HCP 320            // H'(256) | zb(64)
#define KTOP 64
#define EPSBN 1e-5f

typedef __attribute__((ext_vector_type(8))) short short8v;   // 8 bf16
typedef __attribute__((ext_vector_type(4))) float f32x4;

// ---------------- bf16 helpers ----------------
__device__ inline float bf2f(unsigned short u) {
    union { unsigned int i; float f; } c; c.i = ((unsigned int)u) << 16; return c.f;
}
__device__ inline unsigned short f2bf(float f) {
    union { float f; unsigned int i; } c; c.f = f;
    unsigned int r = c.i + 0x7FFFu + ((c.i >> 16) & 1u);
    return (unsigned short)(r >> 16);
}
__device__ inline void split2(float v, unsigned short& hi, unsigned short& lo) {
    hi = f2bf(v);
    lo = f2bf(v - bf2f(hi));
}

// ---------------------------------------------------------------------------
// split_x: fp32 [NN,64] -> hi/lo bf16 pair (one-time, layer-1 A operand)
// ---------------------------------------------------------------------------
__global__ __launch_bounds__(256) void split_x(
    const float* __restrict__ X,
    unsigned short* __restrict__ Xhi, unsigned short* __restrict__ Xlo)
{
    size_t i8 = ((size_t)blockIdx.x * 256 + threadIdx.x) * 8;
    float4 a0 = *(const float4*)(X + i8);
    float4 a1 = *(const float4*)(X + i8 + 4);
    float av[8] = {a0.x, a0.y, a0.z, a0.w, a1.x, a1.y, a1.z, a1.w};
    short8v vh, vl;
    #pragma unroll
    for (int j = 0; j < 8; j++) {
        unsigned short h, l;
        split2(av[j], h, l);
        vh[j] = (short)h; vl[j] = (short)l;
    }
    *(short8v*)(Xhi + i8) = vh;
    *(short8v*)(Xlo + i8) = vl;
}

// ---------------------------------------------------------------------------
// prep (parallelized, 65 blocks) — see round-9 layout comments.
// ---------------------------------------------------------------------------
__global__ __launch_bounds__(256) void prep(
    const float* __restrict__ Wq, const float* __restrict__ bq,
    const float* __restrict__ Wk, const float* __restrict__ bk,
    const float* __restrict__ Wv, const float* __restrict__ bv,
    const float* __restrict__ Ws, const float* __restrict__ bs,
    const float* __restrict__ We, const float* __restrict__ tW,
    const float* __restrict__ Wb,
    unsigned short* __restrict__ WThi, unsigned short* __restrict__ WTlo,
    float* __restrict__ bcat,
    unsigned short* __restrict__ tWThi, unsigned short* __restrict__ tWTlo,
    float* __restrict__ Wbf, float* __restrict__ stats)
{
    const int t = threadIdx.x, b = blockIdx.x;
    if (b < 16) {
        int n = b * 64 + (t >> 2);
        int cc = n & 255;
        const float* src = (n < 256) ? Wq : (n < 512) ? Wk : (n < 768) ? Wv : Ws;
        int k0 = (t & 3) * 16;
        #pragma unroll
        for (int k = k0; k < k0 + 16; k++) {
            unsigned short h, l;
            split2(src[k * 256 + cc], h, l);
            WThi[n * 64 + k] = h; WTlo[n * 64 + k] = l;
        }
    } else if (b < 32) {
        int idx = (b - 16) * 256 + t;
        int k = idx >> 6, o = idx & 63;
        int h = o >> 4, f = o & 15;
        const float* wq = Wq + k * 256 + h * 64;
        const float* we = We + f * 256 + h * 64;
        float s = 0.f;
        #pragma unroll
        for (int d = 0; d < 64; d++) s += wq[d] * we[d];
        unsigned short hh, ll;
        split2(s, hh, ll);
        WThi[(1024 + o) * 64 + k] = hh; WTlo[(1024 + o) * 64 + k] = ll;
    } else if (b < 48) {
        int idx = (b - 32) * 256 + t;
        int kp = idx >> 6, n = idx & 63;
        int h = kp >> 4, f = kp & 15;
        const float* we = We + f * 256 + h * 64;
        const float* tw = tW + (h * 64) * 64 + n;
        float s = 0.f;
        #pragma unroll
        for (int d = 0; d < 64; d++) s += we[d] * tw[d * 64];
        unsigned short hh, ll;
        split2(s, hh, ll);
        tWThi[n * HCP + 256 + kp] = hh; tWTlo[n * HCP + 256 + kp] = ll;
    } else if (b < 64) {
        int base = (b - 48) * 1024 + t * 4;
        #pragma unroll
        for (int i = 0; i < 4; i++) {
            int idx = base + i;
            int n = idx >> 8, k = idx & 255;
            unsigned short h, l;
            split2(tW[k * 64 + n], h, l);
            tWThi[n * HCP + k] = h; tWTlo[n * HCP + k] = l;
        }
    } else {
        if (t < 128) stats[t] = 0.f;
        Wbf[t]       = Wb[t]       + Wb[512 + t];   // w13
        Wbf[256 + t] = Wb[256 + t] - Wb[512 + t];   // w23
        for (int c = t; c < 1024; c += 256) {
            int cc = c & 255;
            bcat[c] = (c < 256) ? bq[cc] : (c < 512) ? bk[cc] : (c < 768) ? bv[cc] : bs[cc];
        }
        if (t < 64) {
            int h = t >> 4, f = t & 15;
            const float* we = We + f * 256 + h * 64;
            float s = 0.f, sb = 0.f;
            #pragma unroll
            for (int d = 0; d < 64; d++) {
                s  += we[d] * (Wb[h * 64 + d] + Wb[512 + h * 64 + d]);
                sb += we[d] * bq[h * 64 + d];
            }
            Wbf[512 + t] = s;        // we13
            bcat[1024 + t] = sb;     // qe bias
        }
    }
}

// ---------------------------------------------------------------------------
// MFMA projection (split-bf16): C_bf16[M,1088] = A[M,64] @ W[64,1088] + bcat
// ---------------------------------------------------------------------------
__global__ __launch_bounds__(256) void proj_mfma(
    const unsigned short* __restrict__ Ahi, const unsigned short* __restrict__ Alo,
    const unsigned short* __restrict__ WThi, const unsigned short* __restrict__ WTlo,
    const float* __restrict__ bcat, unsigned short* __restrict__ C)
{
    __shared__ char smem[32768];
    unsigned short* AhiL = (unsigned short*)smem;            // [64][64]
    unsigned short* AloL = AhiL + 4096;
    unsigned short* WhiL = AloL + 4096;
    unsigned short* WloL = WhiL + 4096;
    float* CL = (float*)smem;                                // [64][68] reuse
    const int t = threadIdx.x;
    const int n0 = blockIdx.x * 64;
    const int row0 = blockIdx.y * 64;

    #pragma unroll
    for (int g = 0; g < 2; g++) {
        int idx = t * 8 + g * 2048;
        int r = idx >> 6, c = idx & 63;
        int ch = (c >> 3) ^ (r & 7);
        *(short8v*)(AhiL + r * 64 + ch * 8) =
            *(const short8v*)(Ahi + (size_t)(row0 + r) * 64 + c);
        *(short8v*)(AloL + r * 64 + ch * 8) =
            *(const short8v*)(Alo + (size_t)(row0 + r) * 64 + c);
        *(short8v*)(WhiL + r * 64 + ch * 8) =
            *(const short8v*)(WThi + (size_t)(n0 + r) * 64 + c);
        *(short8v*)(WloL + r * 64 + ch * 8) =
            *(const short8v*)(WTlo + (size_t)(n0 + r) * 64 + c);
    }
    __syncthreads();

    const int w = t >> 6, l = t & 63;
    const int lr = l & 15, lg = l >> 4, ls = l & 7;
    f32x4 acc[4] = {};
    #pragma unroll
    for (int kk = 0; kk < 2; kk++) {
        int ch = (kk * 4 + lg) ^ ls;
        short8v ah = *(short8v*)(AhiL + (w * 16 + lr) * 64 + ch * 8);
        short8v al = *(short8v*)(AloL + (w * 16 + lr) * 64 + ch * 8);
        #pragma unroll
        for (int nt = 0; nt < 4; nt++) {
            short8v bh = *(short8v*)(WhiL + (nt * 16 + lr) * 64 + ch * 8);
            short8v bl = *(short8v*)(WloL + (nt * 16 + lr) * 64 + ch * 8);
            acc[nt] = __builtin_amdgcn_mfma_f32_16x16x32_bf16(ah, bh, acc[nt], 0, 0, 0);
            acc[nt] = __builtin_amdgcn_mfma_f32_16x16x32_bf16(al, bh, acc[nt], 0, 0, 0);
            acc[nt] = __builtin_amdgcn_mfma_f32_16x16x32_bf16(ah, bl, acc[nt], 0, 0, 0);
        }
    }
    __syncthreads();
    #pragma unroll
    for (int nt = 0; nt < 4; nt++)
        #pragma unroll
        for (int r = 0; r < 4; r++)
            CL[(w * 16 + lg * 4 + r) * 68 + nt * 16 + lr] = acc[nt][r];
    __syncthreads();
    {
        int r = t >> 2, cb = (t & 3) * 16;
        #pragma unroll
        for (int jj = 0; jj < 2; jj++) {
            f32x4 p0 = *(f32x4*)(CL + r * 68 + cb + jj * 8);
            f32x4 p1 = *(f32x4*)(CL + r * 68 + cb + jj * 8 + 4);
            float4 b0 = *(const float4*)(bcat + n0 + cb + jj * 8);
            float4 b1 = *(const float4*)(bcat + n0 + cb + jj * 8 + 4);
            short8v o;
            o[0] = (short)f2bf(p0[0] + b0.x); o[1] = (short)f2bf(p0[1] + b0.y);
            o[2] = (short)f2bf(p0[2] + b0.z); o[3] = (short)f2bf(p0[3] + b0.w);
            o[4] = (short)f2bf(p1[0] + b1.x); o[5] = (short)f2bf(p1[1] + b1.y);
            o[6] = (short)f2bf(p1[2] + b1.z); o[7] = (short)f2bf(p1[3] + b1.w);
            *(short8v*)(C + (size_t)(row0 + r) * NCAT + n0 + cb + jj * 8) = o;
        }
    }
}

// ---------------------------------------------------------------------------
// MFMA transform (split-bf16): T_f32[M,64] = relu(A[M,320] @ W[320,64] + b)
// ---------------------------------------------------------------------------
__global__ __launch_bounds__(256) void gemm_t(
    const unsigned short* __restrict__ Ahi, const unsigned short* __restrict__ Alo,
    const unsigned short* __restrict__ WThi, const unsigned short* __restrict__ WTlo,
    const float* __restrict__ bias, float* __restrict__ Tout,
    float* __restrict__ stats)
{
    __shared__ char smem[32768];
    unsigned short* AhiL = (unsigned short*)smem;
    unsigned short* AloL = AhiL + 4096;
    unsigned short* WhiL = AloL + 4096;
    unsigned short* WloL = WhiL + 4096;
    float* CL = (float*)smem;
    const int t = threadIdx.x;
    const int row0 = blockIdx.x * 64;
    const int w = t >> 6, l = t & 63;
    const int lr = l & 15, lg = l >> 4, ls = l & 7;
    f32x4 acc[4] = {};
    for (int kt = 0; kt < 5; kt++) {
        if (kt) __syncthreads();
        #pragma unroll
        for (int g = 0; g < 2; g++) {
            int idx = t * 8 + g * 2048;
            int r = idx >> 6, c = idx & 63;
            int ch = (c >> 3) ^ (r & 7);
            *(short8v*)(AhiL + r * 64 + ch * 8) =
                *(const short8v*)(Ahi + (size_t)(row0 + r) * HCP + kt * 64 + c);
            *(short8v*)(AloL + r * 64 + ch * 8) =
                *(const short8v*)(Alo + (size_t)(row0 + r) * HCP + kt * 64 + c);
            *(short8v*)(WhiL + r * 64 + ch * 8) =
                *(const short8v*)(WThi + r * HCP + kt * 64 + c);
            *(short8v*)(WloL + r * 64 + ch * 8) =
                *(const short8v*)(WTlo + r * HCP + kt * 64 + c);
        }
        __syncthreads();
        #pragma unroll
        for (int kk = 0; kk < 2; kk++) {
            int ch = (kk * 4 + lg) ^ ls;
            short8v ah = *(short8v*)(AhiL + (w * 16 + lr) * 64 + ch * 8);
            short8v al = *(short8v*)(AloL + (w * 16 + lr) * 64 + ch * 8);
            #pragma unroll
            for (int nt = 0; nt < 4; nt++) {
                short8v bh = *(short8v*)(WhiL + (nt * 16 + lr) * 64 + ch * 8);
                short8v bl = *(short8v*)(WloL + (nt * 16 + lr) * 64 + ch * 8);
                acc[nt] = __builtin_amdgcn_mfma_f32_16x16x32_bf16(ah, bh, acc[nt], 0, 0, 0);
                acc[nt] = __builtin_amdgcn_mfma_f32_16x16x32_bf16(al, bh, acc[nt], 0, 0, 0);
                acc[nt] = __builtin_amdgcn_mfma_f32_16x16x32_bf16(ah, bl, acc[nt], 0, 0, 0);
            }
        }
    }
    __syncthreads();
    #pragma unroll
    for (int nt = 0; nt < 4; nt++)
        #pragma unroll
        for (int r = 0; r < 4; r++)
            CL[(w * 16 + lg * 4 + r) * 68 + nt * 16 + lr] = acc[nt][r];
    __syncthreads();
    {
        int r = t >> 2, cb = (t & 3) * 16;
        #pragma unroll
        for (int jj = 0; jj < 4; jj++) {
            f32x4 p = *(f32x4*)(CL + r * 68 + cb + jj * 4);
            float4 bb = *(const float4*)(bias + cb + jj * 4);
            float4 o;
            o.x = fmaxf(p[0] + bb.x, 0.f); o.y = fmaxf(p[1] + bb.y, 0.f);
            o.z = fmaxf(p[2] + bb.z, 0.f); o.w = fmaxf(p[3] + bb.w, 0.f);
            *(float4*)(Tout + (size_t)(row0 + r) * 64 + cb + jj * 4) = o;
        }
    }
    if (t < 64) {
        float bb = bias[t];
        float s = 0.f, s2 = 0.f;
        #pragma unroll 8
        for (int r = 0; r < 64; r++) {
            float v = fmaxf(CL[r * 68 + t] + bb, 0.f);
            s += v; s2 += v * v;
        }
        atomicAdd(&stats[t], s);
        atomicAdd(&stats[64 + t], s2);
    }
}

// ---------------------------------------------------------------------------
// Attention + beta gate. ONE node per 64-lane wave, 4 ch/lane (low VGPR,
// 8 waves/SIMD target). Output H'[NN,320] = [beta*xr+(1-b)*attnV | (1-b)*z].
// ---------------------------------------------------------------------------
__global__ __launch_bounds__(256, 8) void attn_fused(
    const unsigned short* __restrict__ C,
    const float* __restrict__ Wbf,
    const int* __restrict__ srcIdx, const float* __restrict__ EA,
    unsigned short* __restrict__ Hhi, unsigned short* __restrict__ Hlo)
{
    const int t = threadIdx.x;
    const int lane = t & 63;
    const int wave = t >> 6;
    const int bid = blockIdx.x;
    const int swz = (bid & 7) * 1024 + (bid >> 3);  // 8192 blocks, XCD chunks
    const int n = swz * 4 + wave;                   // 4 nodes per block
    const int c0 = lane * 4;                        // 4 channels/lane
    const int h = lane >> 4;                        // head
    const int fi = lane & 15;                       // edge-feature index

    const unsigned short* rowN = C + (size_t)n * NCAT;
    ushort4 qv = *(const ushort4*)(rowN + c0);
    float q0 = bf2f(qv.x), q1 = bf2f(qv.y), q2 = bf2f(qv.z), q3 = bf2f(qv.w);
    float qe_l = bf2f(rowN[1024 + h * 16 + fi]);

    const int ebase = n * DEG;
    int sj = srcIdx[ebase + (lane & 7)];
    int ss[DEG];
    #pragma unroll
    for (int j = 0; j < DEG; j++) ss[j] = __shfl(sj, j);

    // batched K + EA loads (all in flight)
    ushort4 kv[DEG];
    float eav[DEG];
    #pragma unroll
    for (int j = 0; j < DEG; j++) {
        kv[j] = *(const ushort4*)(C + (size_t)ss[j] * NCAT + 256 + c0);
        eav[j] = EA[(size_t)(ebase + j) * 16 + fi];
    }
    float alpha[DEG];
    #pragma unroll
    for (int j = 0; j < DEG; j++) {
        float d = eav[j] * qe_l
                + q0 * bf2f(kv[j].x) + q1 * bf2f(kv[j].y)
                + q2 * bf2f(kv[j].z) + q3 * bf2f(kv[j].w);
        d += __shfl_xor(d, 1); d += __shfl_xor(d, 2);
        d += __shfl_xor(d, 4); d += __shfl_xor(d, 8);
        alpha[j] = d * 0.125f;                      // 1/sqrt(64)
    }
    float mx = alpha[0];
    #pragma unroll
    for (int j = 1; j < DEG; j++) mx = fmaxf(mx, alpha[j]);
    float wsum = 0.f;
    #pragma unroll
    for (int j = 0; j < DEG; j++) { alpha[j] = expf(alpha[j] - mx); wsum += alpha[j]; }
    float inv = 1.f / wsum;

    // V gather + weighted sum; z accumulation (z index == lane)
    float o0 = 0.f, o1 = 0.f, o2 = 0.f, o3 = 0.f, eg = 0.f;
    #pragma unroll
    for (int j = 0; j < DEG; j++) {
        float wj = alpha[j] * inv;
        eg += wj * eav[j];
        ushort4 vv = *(const ushort4*)(C + (size_t)ss[j] * NCAT + 512 + c0);
        o0 += wj * bf2f(vv.x); o1 += wj * bf2f(vv.y);
        o2 += wj * bf2f(vv.z); o3 += wj * bf2f(vv.w);
    }

    ushort4 sv = *(const ushort4*)(rowN + 768 + c0);
    float xr0 = bf2f(sv.x), xr1 = bf2f(sv.y), xr2 = bf2f(sv.z), xr3 = bf2f(sv.w);

    // beta logit: o.w13 + xr.w23 + z.we13 (we13 index == lane)
    float part = eg * Wbf[512 + lane];
    {
        f32x4 w13 = *(const f32x4*)(Wbf + c0);
        f32x4 w23 = *(const f32x4*)(Wbf + 256 + c0);
        part += o0 * w13[0] + o1 * w13[1] + o2 * w13[2] + o3 * w13[3];
        part += xr0 * w23[0] + xr1 * w23[1] + xr2 * w23[2] + xr3 * w23[3];
    }
    part += __shfl_xor(part, 1);  part += __shfl_xor(part, 2);
    part += __shfl_xor(part, 4);  part += __shfl_xor(part, 8);
    part += __shfl_xor(part, 16); part += __shfl_xor(part, 32);
    float beta = 1.f / (1.f + expf(-part));
    float omb = 1.f - beta;

    ushort4 hh, hl;
    split2(beta * xr0 + omb * o0, hh.x, hl.x);
    split2(beta * xr1 + omb * o1, hh.y, hl.y);
    split2(beta * xr2 + omb * o2, hh.z, hl.z);
    split2(beta * xr3 + omb * o3, hh.w, hl.w);
    *(ushort4*)(Hhi + (size_t)n * HCP + c0) = hh;
    *(ushort4*)(Hlo + (size_t)n * HCP + c0) = hl;

    unsigned short zh, zl;
    split2(omb * eg, zh, zl);
    Hhi[(size_t)n * HCP + 256 + lane] = zh;
    Hlo[(size_t)n * HCP + 256 + lane] = zl;
}

// ---------------------------------------------------------------------------
// BN apply: normalize + emit bf16 hi/lo; optional f32 write (pool needs it)
// ---------------------------------------------------------------------------
__global__ __launch_bounds__(256) void bn_apply(
    float* __restrict__ T, const float* __restrict__ stats,
    const float* __restrict__ g, const float* __restrict__ b,
    unsigned short* __restrict__ Thi, unsigned short* __restrict__ Tlo,
    int wf32)
{
    int i = blockIdx.x * 256 + threadIdx.x;
    int c = i & 63;
    float mean = stats[c] * (1.f / NN);
    float var  = stats[64 + c] * (1.f / NN) - mean * mean;
    float v = T[i];
    float r = g[c] * (v - mean) * rsqrtf(var + EPSBN) + b[c];
    if (wf32) T[i] = r;
    unsigned short h, l;
    split2(r, h, l);
    Thi[i] = h; Tlo[i] = l;
}

// ---------------------------------------------------------------------------
// TopK pooling + readout + MLP head. One block (128 threads) per graph.
// ---------------------------------------------------------------------------
__global__ __launch_bounds__(128) void pool_mlp(
    const float* __restrict__ Hn, const float* __restrict__ pw,
    const float* __restrict__ W1, const float* __restrict__ b1,
    const float* __restrict__ W2, const float* __restrict__ b2,
    const float* __restrict__ W3, const float* __restrict__ b3,
    float* __restrict__ out)
{
    __shared__ float sh[128][65];
    __shared__ float spw[64];
    __shared__ float sc[128];
    __shared__ float sscale[128];
    __shared__ int   skeep[128];
    __shared__ float rmax[2][64], rsum[2][64];
    __shared__ float srep[128];
    __shared__ float sh1[256];
    __shared__ float sh2[128];
    __shared__ float wred[2];
    const int g = blockIdx.x, t = threadIdx.x;

    for (int i = t; i < 128 * 64; i += 128) sh[i >> 6][i & 63] = Hn[(size_t)g * 128 * 64 + i];
    if (t < 64) spw[t] = pw[t];
    __syncthreads();

    float nw = 0.f;
    #pragma unroll
    for (int i = 0; i < 64; i++) { float w = spw[i]; nw += w * w; }
    float invn = rsqrtf(nw);

    float s = 0.f;
    #pragma unroll
    for (int i = 0; i < 64; i++) s += sh[t][i] * spw[i];
    s *= invn;
    sc[t] = s;
    __syncthreads();

    int rank = 0;
    for (int m = 0; m < 128; m++) {
        float sm = sc[m];
        rank += (sm > s) || (sm == s && m < t);
    }
    skeep[t] = (rank < KTOP);
    sscale[t] = tanhf(s);
    __syncthreads();

    {
        int c = t & 63, half = t >> 6;
        float mxv = -1e30f, sm = 0.f;
        for (int r = half * 64; r < half * 64 + 64; r++) {
            if (skeep[r]) {
                float v = sh[r][c] * sscale[r];
                mxv = fmaxf(mxv, v); sm += v;
            }
        }
        rmax[half][c] = mxv; rsum[half][c] = sm;
    }
    __syncthreads();
    if (t < 64) {
        srep[t] = fmaxf(rmax[0][t], rmax[1][t]);
        srep[64 + t] = (rsum[0][t] + rsum[1][t]) * (1.f / KTOP);
    }
    __syncthreads();

    #pragma unroll
    for (int jj = 0; jj < 2; jj++) {
        int j = t + jj * 128;
        float a = b1[j];
        for (int c2 = 0; c2 < 128; c2++) a += srep[c2] * W1[c2 * 256 + j];
        sh1[j] = fmaxf(a, 0.f);
    }
    __syncthreads();
    {
        float a = b2[t];
        for (int c2 = 0; c2 < 256; c2++) a += sh1[c2] * W2[c2 * 128 + t];
        sh2[t] = fmaxf(a, 0.f);
    }
    __syncthreads();
    float p = sh2[t] * W3[t];
    p += __shfl_xor(p, 1);  p += __shfl_xor(p, 2);  p += __shfl_xor(p, 4);
    p += __shfl_xor(p, 8);  p += __shfl_xor(p, 16); p += __shfl_xor(p, 32);
    if ((t & 63) == 0) wred[t >> 6] = p;
    __syncthreads();
    if (t == 0) out[g] = wred[0] + wred[1] + b3[0];
}

// ---------------------------------------------------------------------------
extern "C" void kernel_launch(void* const* d_in, const int* in_sizes, int n_in,
                              void* d_out, int out_size, void* d_ws, size_t ws_size,
                              hipStream_t stream)
{
    const float* x    = (const float*)d_in[0];
    const int*   ei   = (const int*)  d_in[1];
    const float* ea   = (const float*)d_in[2];
    const int*   srcI = ei;
    const float* Wq1 = (const float*)d_in[4];  const float* bq1 = (const float*)d_in[5];
    const float* Wk1 = (const float*)d_in[6];  const float* bk1 = (const float*)d_in[7];
    const float* Wv1 = (const float*)d_in[8];  const float* bv1 = (const float*)d_in[9];
    const float* We1 = (const float*)d_in[10];
    const float* Ws1 = (const float*)d_in[11]; const float* bs1 = (const float*)d_in[12];
    const float* Wb1 = (const float*)d_in[13];
    const float* t1W = (const float*)d_in[14]; const float* t1b = (const float*)d_in[15];
    const float* g1  = (const float*)d_in[16]; const float* be1 = (const float*)d_in[17];
    const float* Wq2 = (const float*)d_in[18]; const float* bq2 = (const float*)d_in[19];
    const float* Wk2 = (const float*)d_in[20]; const float* bk2 = (const float*)d_in[21];
    const float* Wv2 = (const float*)d_in[22]; const float* bv2 = (const float*)d_in[23];
    const float* We2 = (const float*)d_in[24];
    const float* Ws2 = (const float*)d_in[25]; const float* bs2 = (const float*)d_in[26];
    const float* Wb2 = (const float*)d_in[27];
    const float* t2W = (const float*)d_in[28]; const float* t2b = (const float*)d_in[29];
    const float* g2  = (const float*)d_in[30]; const float* be2 = (const float*)d_in[31];
    const float* pw  = (const float*)d_in[32];
    const float* l1W = (const float*)d_in[33]; const float* l1b = (const float*)d_in[34];
    const float* l2W = (const float*)d_in[35]; const float* l2b = (const float*)d_in[36];
    const float* l3W = (const float*)d_in[37]; const float* l3b = (const float*)d_in[38];

    char* ws = (char*)d_ws;
    unsigned short* C   = (unsigned short*)ws;                     // [NN,1088] bf16
    unsigned short* Hhi = (unsigned short*)(ws + (size_t)NN * NCAT * 2); // [NN,320]
    unsigned short* Hlo = Hhi + (size_t)NN * HCP;
    float* bT    = (float*)(Hlo + (size_t)NN * HCP);               // [NN,64] f32
    unsigned short* bThi = (unsigned short*)(bT + (size_t)NN * 64);
    unsigned short* bTlo = bThi + (size_t)NN * 64;
    unsigned short* Xhi  = bTlo + (size_t)NN * 64;
    unsigned short* Xlo  = Xhi + (size_t)NN * 64;
    float* bcat  = (float*)(Xlo + (size_t)NN * 64);                // [1088]
    float* stats = bcat + NCAT;                                    // [128]
    float* Wbf   = stats + 128;                                    // [576]
    unsigned short* WThi  = (unsigned short*)(Wbf + 576);          // [1088][64]
    unsigned short* WTlo  = WThi + (size_t)NCAT * 64;
    unsigned short* tWThi = WTlo + (size_t)NCAT * 64;              // [64][320]
    unsigned short* tWTlo = tWThi + 64 * HCP;

    const dim3 blk(256);
    const dim3 gProj(17, 512);

    // ---- layer 1 ----
    split_x<<<NN * 64 / (256 * 8), blk, 0, stream>>>(x, Xhi, Xlo);
    prep<<<65, blk, 0, stream>>>(Wq1, bq1, Wk1, bk1, Wv1, bv1, Ws1, bs1, We1, t1W, Wb1,
                                 WThi, WTlo, bcat, tWThi, tWTlo, Wbf, stats);
    proj_mfma<<<gProj, blk, 0, stream>>>(Xhi, Xlo, WThi, WTlo, bcat, C);
    attn_fused<<<NN / 4, blk, 0, stream>>>(C, Wbf, srcI, ea, Hhi, Hlo);
    gemm_t<<<512, blk, 0, stream>>>(Hhi, Hlo, tWThi, tWTlo, t1b, bT, stats);
    bn_apply<<<NN * 64 / 256, blk, 0, stream>>>(bT, stats, g1, be1, bThi, bTlo, 0);

    // ---- layer 2 ----
    prep<<<65, blk, 0, stream>>>(Wq2, bq2, Wk2, bk2, Wv2, bv2, Ws2, bs2, We2, t2W, Wb2,
                                 WThi, WTlo, bcat, tWThi, tWTlo, Wbf, stats);
    proj_mfma<<<gProj, blk, 0, stream>>>(bThi, bTlo, WThi, WTlo, bcat, C);
    attn_fused<<<NN / 4, blk, 0, stream>>>(C, Wbf, srcI, ea, Hhi, Hlo);
    gemm_t<<<512, blk, 0, stream>>>(Hhi, Hlo, tWThi, tWTlo, t2b, bT, stats);
    bn_apply<<<NN * 64 / 256, blk, 0, stream>>>(bT, stats, g2, be2, bThi, bTlo, 1);

    // ---- pooling + head ----
    pool_mlp<<<NG, 128, 0, stream>>>(bT, pw, l1W, l1b, l2W, l2b, l3W, l3b,
                                     (float*)d_out);
}